// Round 14
// baseline (258.186 us; speedup 1.0000x reference)
//
#include <hip/hip_runtime.h>

// Problem constants
#define T_ 128
#define B_ 64
#define NH_ 64
#define NC_ 10

__device__ __forceinline__ float sigmoid_f(float x) {
    return 1.0f / (1.0f + __expf(-x));
}
__device__ __forceinline__ float tanh_f(float x) {
    return 1.0f - 2.0f / (1.0f + __expf(2.0f * x));
}

// ---------------------------------------------------------------------------
// Gray-like systolic walk over all 64 xor-masks, chosen so that almost every
// hop is a single VALU DPP op:
//   per-16 block walk S = 1,2,1,7,1,2,1,15,1,2,1,7,1,2,1   (all DPP)
//     1  -> quad_perm(1,0,3,2)  (0xB1)
//     2  -> quad_perm(2,3,0,1)  (0x4E)
//     7  -> row_half_mirror     (0x141)   i -> i^7 within 8
//     15 -> row_mirror          (0x140)   i -> i^15 within 16
//   block joins (i=16,32,48): xor16 (ds_swizzle), xor32 (shfl), xor16
// Only 3 LDS ops on the 63-hop chain (R13's mapping had 7 — that was the
// latency bug). Cumulative-mask table M64 below; weights are pre-permuted
// by the fold kernel so each dot completes fully in-lane.
// ---------------------------------------------------------------------------
__device__ const int M64tab[64] = {
    0,  1,  3,  2,  5,  4,  6,  7,  8,  9,  11, 10, 13, 12, 14, 15,
    31, 30, 28, 29, 26, 27, 25, 24, 23, 22, 20, 21, 18, 19, 17, 16,
    48, 49, 51, 50, 53, 52, 54, 55, 56, 57, 59, 58, 61, 60, 62, 63,
    47, 46, 44, 45, 42, 43, 41, 40, 39, 38, 36, 37, 34, 35, 33, 32};

__device__ __forceinline__ float dpp_xor1(float x) {
    return __int_as_float(__builtin_amdgcn_mov_dpp(__float_as_int(x), 0xB1, 0xF, 0xF, false));
}
__device__ __forceinline__ float dpp_xor2(float x) {
    return __int_as_float(__builtin_amdgcn_mov_dpp(__float_as_int(x), 0x4E, 0xF, 0xF, false));
}
__device__ __forceinline__ float dpp_xor7(float x) {
    return __int_as_float(__builtin_amdgcn_mov_dpp(__float_as_int(x), 0x141, 0xF, 0xF, false));
}
__device__ __forceinline__ float dpp_xor15(float x) {
    return __int_as_float(__builtin_amdgcn_mov_dpp(__float_as_int(x), 0x140, 0xF, 0xF, false));
}
__device__ __forceinline__ float swz_xor16(float x) {
    return __int_as_float(__builtin_amdgcn_ds_swizzle(__float_as_int(x), 0x401F));
}
// i is compile-time after unroll; branches fold to one instruction.
__device__ __forceinline__ float swapstep(float v, int i) {
    const int im = i & 15;
    if (im == 0) return (i == 32) ? __shfl_xor(v, 32, 64) : swz_xor16(v);
    if (im & 1) return dpp_xor1(v);
    if (im == 8) return dpp_xor15(v);
    if ((im & 3) == 2) return dpp_xor2(v);
    return dpp_xor7(v);   // im == 4 or 12
}

// ---------------------------------------------------------------------------
// Kernel 1: per-frame 3x3 VALID conv -> sigmoid(logit-thr) -> spatial mean.
// grid = 8192, 256 threads. (unchanged)
// ---------------------------------------------------------------------------
#define IMP 68
__global__ __launch_bounds__(256) void conv_feat(const float* __restrict__ img,
                                                 const float* __restrict__ cw,
                                                 const float* __restrict__ cb,
                                                 const float* __restrict__ thr,
                                                 float* __restrict__ feat) {
    __shared__ __align__(16) float im[64 * IMP];
    __shared__ float wsum[4];
    const int tid = threadIdx.x;
    const float* src = img + (size_t)blockIdx.x * 4096;
#pragma unroll
    for (int i = 0; i < 4; i++) {
        const int idx = i * 256 + tid;
        const int row = idx >> 4, c4 = idx & 15;
        *(float4*)&im[row * IMP + c4 * 4] = *(const float4*)&src[idx * 4];
    }
    const float w0 = cw[0], w1 = cw[1], w2 = cw[2], w3 = cw[3], w4 = cw[4],
                w5 = cw[5], w6 = cw[6], w7 = cw[7], w8 = cw[8];
    const float bias = cb[0] - thr[0];
    __syncthreads();

    const int r  = tid >> 2;
    const int c0 = (tid & 3) * 16;
    float sum = 0.0f;
    if (r < 62) {
        const int ncols = (c0 == 48) ? 14 : 16;
        float acc[16];
#pragma unroll
        for (int x = 0; x < 16; x++) acc[x] = bias;
#pragma unroll
        for (int dr = 0; dr < 3; dr++) {
            float rb[20];
#pragma unroll
            for (int j = 0; j < 5; j++) {
                float4 v = *(const float4*)&im[(r + dr) * IMP + c0 + j * 4];
                rb[j * 4 + 0] = v.x; rb[j * 4 + 1] = v.y;
                rb[j * 4 + 2] = v.z; rb[j * 4 + 3] = v.w;
            }
            const float k0 = (dr == 0) ? w0 : (dr == 1) ? w3 : w6;
            const float k1 = (dr == 0) ? w1 : (dr == 1) ? w4 : w7;
            const float k2 = (dr == 0) ? w2 : (dr == 1) ? w5 : w8;
#pragma unroll
            for (int x = 0; x < 16; x++) {
                acc[x] = fmaf(rb[x], k0, acc[x]);
                acc[x] = fmaf(rb[x + 1], k1, acc[x]);
                acc[x] = fmaf(rb[x + 2], k2, acc[x]);
            }
        }
#pragma unroll
        for (int x = 0; x < 16; x++)
            if (x < ncols) sum += sigmoid_f(acc[x]);
    }
#pragma unroll
    for (int off = 32; off >= 1; off >>= 1) sum += __shfl_down(sum, off, 64);
    const int wv = tid >> 6, ln = tid & 63;
    if (ln == 0) wsum[wv] = sum;
    __syncthreads();
    if (tid == 0)
        feat[blockIdx.x] = (wsum[0] + wsum[1] + wsum[2] + wsum[3]) * (1.0f / 3844.0f);
}

// ---------------------------------------------------------------------------
// Kernel 2: fold fc+lw per gate AND scatter both weight matrices into the
// systolic layout: store A[n][j] (and ew[n][j]) at walk position i where
// M64tab[i] == n^j:  At[g][i>>2][n][i&3]. grid = 4, 256 threads.
// ---------------------------------------------------------------------------
struct FuseArgs {
    const float* fcw[4];
    const float* fcb[4];
    const float* lw[4];
    const float* lb[4];
    const float* ew[4];
};

__global__ __launch_bounds__(256) void fuse_kernel(FuseArgs a, float* __restrict__ At,
                                                   float* __restrict__ Et,
                                                   float* __restrict__ Vall,
                                                   float* __restrict__ Call) {
    const int g = blockIdx.x;
    const float* fcw = a.fcw[g];
    const float* fcb = a.fcb[g];
    const float* lw  = a.lw[g];
    const float* lb  = a.lb[g];
    const float* ew  = a.ew[g];
    __shared__ float fcs[64 * 65];
    __shared__ float fbs[64];
    for (int i = threadIdx.x; i < 64 * 65; i += 256) fcs[i] = fcw[i];
    if (threadIdx.x < 64) fbs[threadIdx.x] = fcb[threadIdx.x];
    __syncthreads();

    const int n = threadIdx.x >> 2;
    const int j0 = (threadIdx.x & 3) * 16;
    float lrow[64];
#pragma unroll
    for (int k = 0; k < 64; k++) lrow[k] = lw[n * 64 + k];

    for (int j = j0; j < j0 + 16; j++) {
        float s = 0.0f;
#pragma unroll
        for (int k = 0; k < 64; k++) s = fmaf(lrow[k], fcs[k * 65 + j + 1], s);
        const int m = n ^ j;
        int i = 0;
        for (int t2 = 0; t2 < 64; t2++)
            if (M64tab[t2] == m) { i = t2; break; }
        At[g * 4096 + (i >> 2) * 256 + n * 4 + (i & 3)] = s;
        Et[g * 4096 + (i >> 2) * 256 + n * 4 + (i & 3)] = ew[n * 64 + j];
    }
    if ((threadIdx.x & 3) == 0) {
        float sv = 0.0f, sc = 0.0f;
#pragma unroll
        for (int k = 0; k < 64; k++) {
            sv = fmaf(lrow[k], fcs[k * 65], sv);
            sc = fmaf(lrow[k], fbs[k], sc);
        }
        Vall[g * 64 + n] = sv;
        Call[g * 64 + n] = sc + lb[n];
    }
}

// ---------------------------------------------------------------------------
// Kernel 3: recurrence + fused classifier — VALU-systolic dots (low-LDS walk).
// 32 blocks x 512 threads = 8 waves (2/SIMD); wave = (row r, gate g);
// lane n owns h[n], c[n] in registers. 64-wide dots complete in-lane via the
// xor walk: 60 DPP (VALU) + 3 LDS hops per stage. ONE barrier per step.
// ---------------------------------------------------------------------------
__global__ __launch_bounds__(512, 1) void recur(
    const float* __restrict__ feat, const float* __restrict__ At,
    const float* __restrict__ Et, const float* __restrict__ Vall,
    const float* __restrict__ Call,
    const float* __restrict__ eb_f, const float* __restrict__ eb_i,
    const float* __restrict__ eb_u, const float* __restrict__ eb_o,
    const float* __restrict__ cls_w, const float* __restrict__ cls_b,
    float* __restrict__ out) {
    const int tid = threadIdx.x;
    const int wave = tid >> 6;
    const int r = wave >> 2;             // row-in-block 0..1
    const int g = wave & 3;              // gate 0..3
    const int n = tid & 63;              // hidden index
    const int b = (blockIdx.x << 1) | r; // batch row
    const float* ebp = (g == 0) ? eb_f : (g == 1) ? eb_i : (g == 2) ? eb_u : eb_o;

    const float4* at4 = (const float4*)At + g * 1024;  // [ib*64 + n]
    const float4* et4 = (const float4*)Et + g * 1024;
    const float vj = Vall[g * 64 + n], cj = Call[g * 64 + n], ebj = ebp[n];

    __shared__ __align__(16) float acts[2][2][4][64];  // [r][t&1][g][n]
    __shared__ float xts[2 * T_];
    __shared__ float hist[2][T_ * 65];                 // 66.6 KB
    __shared__ float cwts[NC_ * 65 + NC_];

    for (int i = tid; i < 2 * T_; i += 512) xts[i] = feat[blockIdx.x * 256 + i];
    for (int i = tid; i < NC_ * 64; i += 512) {
        int c = i >> 6, k = i & 63;
        cwts[c * 65 + k] = cls_w[i];
    }
    if (tid < NC_) cwts[NC_ * 65 + tid] = cls_b[tid];
    float h = 0.0f, cx = 0.0f;           // lane n's state, replicated per wave
    __syncthreads();

    for (int t = 0; t < T_; t++) {
        const float xt = xts[r * T_ + t];

        // ---- stage 1: q = tanh(xt*v + h@A^T + c), systolic in-lane ----
        float vrot = h;
        float acc = 0.0f;
#pragma unroll
        for (int ib = 0; ib < 16; ib++) {
            const float4 wq = at4[ib * 64 + n];
            if (ib != 0) vrot = swapstep(vrot, ib * 4);
            acc = fmaf(wq.x, vrot, acc);
            vrot = swapstep(vrot, ib * 4 + 1); acc = fmaf(wq.y, vrot, acc);
            vrot = swapstep(vrot, ib * 4 + 2); acc = fmaf(wq.z, vrot, acc);
            vrot = swapstep(vrot, ib * 4 + 3); acc = fmaf(wq.w, vrot, acc);
        }
        const float q = tanh_f(fmaf(xt, vj, cj) + acc);

        // ---- stage 2: z = q * sigmoid(q@E^T + eb), systolic in-lane ----
        float urot = q;
        float acc2 = 0.0f;
#pragma unroll
        for (int ib = 0; ib < 16; ib++) {
            const float4 wq = et4[ib * 64 + n];
            if (ib != 0) urot = swapstep(urot, ib * 4);
            acc2 = fmaf(wq.x, urot, acc2);
            urot = swapstep(urot, ib * 4 + 1); acc2 = fmaf(wq.y, urot, acc2);
            urot = swapstep(urot, ib * 4 + 2); acc2 = fmaf(wq.z, urot, acc2);
            urot = swapstep(urot, ib * 4 + 3); acc2 = fmaf(wq.w, urot, acc2);
        }
        const float z = q * sigmoid_f(acc2 + ebj);
        acts[r][t & 1][g][n] = (g == 2) ? tanh_f(z) : sigmoid_f(z);
        __syncthreads();                         // the ONLY barrier per step

        // ---- cell update: every wave, own lane n (bitwise identical) ----
        const float ff = acts[r][t & 1][0][n];
        const float ii = acts[r][t & 1][1][n];
        const float uu = acts[r][t & 1][2][n];
        const float oo = acts[r][t & 1][3][n];
        cx = fmaf(ff, cx, ii * uu);
        h = oo * tanh_f(cx);
        if (g == 0) hist[r][t * 65 + n] = h;
    }
    __syncthreads();  // hist complete

    // fused classifier: 1280 outputs PER ROW, swept by that row's 256 threads
    // (R13 bug: o = j*512+tid left 512 of 1280 outputs unwritten per row)
    const int tid256 = tid & 255;
#pragma unroll
    for (int j = 0; j < 5; j++) {
        const int o = j * 256 + tid256;          // 0..1279
        const int rt = o / 10;
        const int c = o - rt * 10;
        float sacc = cwts[NC_ * 65 + c];
#pragma unroll 16
        for (int k = 0; k < 64; k++)
            sacc = fmaf(hist[r][rt * 65 + k], cwts[c * 65 + k], sacc);
        out[((size_t)rt * B_ + b) * NC_ + c] = sacc;
    }
}

// ---------------------------------------------------------------------------
extern "C" void kernel_launch(void* const* d_in, const int* in_sizes, int n_in,
                              void* d_out, int out_size, void* d_ws, size_t ws_size,
                              hipStream_t stream) {
    const float* images = (const float*)d_in[0];
    const float* thr    = (const float*)d_in[1];
    const float* convw  = (const float*)d_in[2];
    const float* convb  = (const float*)d_in[3];
    const float* fcw[4]; const float* fcb[4]; const float* lw[4]; const float* lb[4];
    const float* ew[4];  const float* eb[4];
    for (int g = 0; g < 4; g++) {
        int base = 4 + g * 6;
        fcw[g] = (const float*)d_in[base + 0];
        fcb[g] = (const float*)d_in[base + 1];
        lw[g]  = (const float*)d_in[base + 2];
        lb[g]  = (const float*)d_in[base + 3];
        ew[g]  = (const float*)d_in[base + 4];
        eb[g]  = (const float*)d_in[base + 5];
    }
    const float* clsw = (const float*)d_in[28];
    const float* clsb = (const float*)d_in[29];

    float* ws   = (float*)d_ws;
    float* feat = ws;            // 8192 floats
    float* At   = ws + 8192;     // 16384 floats (systolic-permuted lw@fc)
    float* Et   = ws + 24576;    // 16384 floats (systolic-permuted ew)
    float* Vall = ws + 40960;    // 256
    float* Call = ws + 41216;    // 256

    conv_feat<<<8192, 256, 0, stream>>>(images, convw, convb, thr, feat);

    FuseArgs fa;
    for (int g = 0; g < 4; g++) {
        fa.fcw[g] = fcw[g]; fa.fcb[g] = fcb[g];
        fa.lw[g] = lw[g];   fa.lb[g] = lb[g];
        fa.ew[g] = ew[g];
    }
    fuse_kernel<<<4, 256, 0, stream>>>(fa, At, Et, Vall, Call);

    recur<<<B_ / 2, 512, 0, stream>>>(feat, At, Et, Vall, Call,
                                      eb[0], eb[1], eb[2], eb[3],
                                      clsw, clsb, (float*)d_out);
}

// Round 15
// 171.170 us; speedup vs baseline: 1.5084x; 1.5084x over previous
//
#include <hip/hip_runtime.h>

// Problem constants
#define T_ 128
#define B_ 64
#define NH_ 64
#define NC_ 10

__device__ __forceinline__ float sigmoid_f(float x) {
    return 1.0f / (1.0f + __expf(-x));
}
__device__ __forceinline__ float tanh_f(float x) {
    return 1.0f - 2.0f / (1.0f + __expf(2.0f * x));
}
// 4-wide partial dot accumulate (inline fn, not macro — R8 lesson)
__device__ __forceinline__ void dot4(const float4 a, const float4 v,
                                     float& p0, float& p1, float& p2, float& p3) {
    p0 = fmaf(a.x, v.x, p0);
    p1 = fmaf(a.y, v.y, p1);
    p2 = fmaf(a.z, v.z, p2);
    p3 = fmaf(a.w, v.w, p3);
}

// ---------------------------------------------------------------------------
// Kernel 1: per-frame 3x3 VALID conv -> sigmoid(logit-thr) -> spatial mean.
// grid = 8192, 256 threads. DIRECT-GLOBAL version: the 16 KB frame fits L1,
// so the old LDS round-trip (4 b128 writes + barrier + 15 b128 reads/thread)
// was pure overhead. Thread = 16-wide output run; 3x20 window loaded straight
// from global (row re-reads are L1 hits). Low VGPR (row buffer reused per
// conv row) keeps ~8 blocks/CU for latency hiding.
// ---------------------------------------------------------------------------
__global__ __launch_bounds__(256) void conv_feat(const float* __restrict__ img,
                                                 const float* __restrict__ cw,
                                                 const float* __restrict__ cb,
                                                 const float* __restrict__ thr,
                                                 float* __restrict__ feat) {
    __shared__ float wsum[4];
    const int tid = threadIdx.x;
    const float* src = img + (size_t)blockIdx.x * 4096;
    const float w0 = cw[0], w1 = cw[1], w2 = cw[2], w3 = cw[3], w4 = cw[4],
                w5 = cw[5], w6 = cw[6], w7 = cw[7], w8 = cw[8];
    const float bias = cb[0] - thr[0];

    const int r  = tid >> 2;          // output row 0..63 (62,63 idle)
    const int c0 = (tid & 3) * 16;    // output col base
    float sum = 0.0f;
    if (r < 62) {
        const int ncols = (c0 == 48) ? 14 : 16;
        // c0=48 tail: only 4 float4s are in-row (cols 48..63); the 5th would
        // read past the frame (and past the buffer on the last frame).
        const int nj = (c0 == 48) ? 4 : 5;
        float acc[16];
#pragma unroll
        for (int x = 0; x < 16; x++) acc[x] = bias;
#pragma unroll
        for (int dr = 0; dr < 3; dr++) {
            float rb[20];
#pragma unroll
            for (int j = 0; j < 5; j++) {
                if (j < nj) {
                    float4 v = *(const float4*)&src[(r + dr) * 64 + c0 + j * 4];
                    rb[j * 4 + 0] = v.x; rb[j * 4 + 1] = v.y;
                    rb[j * 4 + 2] = v.z; rb[j * 4 + 3] = v.w;
                } else {
                    rb[j * 4 + 0] = 0.0f; rb[j * 4 + 1] = 0.0f;
                    rb[j * 4 + 2] = 0.0f; rb[j * 4 + 3] = 0.0f;
                }
            }
            const float k0 = (dr == 0) ? w0 : (dr == 1) ? w3 : w6;
            const float k1 = (dr == 0) ? w1 : (dr == 1) ? w4 : w7;
            const float k2 = (dr == 0) ? w2 : (dr == 1) ? w5 : w8;
#pragma unroll
            for (int x = 0; x < 16; x++) {
                acc[x] = fmaf(rb[x], k0, acc[x]);
                acc[x] = fmaf(rb[x + 1], k1, acc[x]);
                acc[x] = fmaf(rb[x + 2], k2, acc[x]);
            }
        }
#pragma unroll
        for (int x = 0; x < 16; x++)
            if (x < ncols) sum += sigmoid_f(acc[x]);
    }
#pragma unroll
    for (int off = 32; off >= 1; off >>= 1) sum += __shfl_down(sum, off, 64);
    const int wv = tid >> 6, ln = tid & 63;
    if (ln == 0) wsum[wv] = sum;
    __syncthreads();
    if (tid == 0)
        feat[blockIdx.x] = (wsum[0] + wsum[1] + wsum[2] + wsum[3]) * (1.0f / 3844.0f);
}

// ---------------------------------------------------------------------------
// Kernel 2: fold fc+lw per gate (unchanged). grid = 4, 256 threads.
// ---------------------------------------------------------------------------
struct FuseArgs {
    const float* fcw[4];
    const float* fcb[4];
    const float* lw[4];
    const float* lb[4];
};

__global__ __launch_bounds__(256) void fuse_kernel(FuseArgs a, float* __restrict__ Aall,
                                                   float* __restrict__ Vall,
                                                   float* __restrict__ Call) {
    const int g = blockIdx.x;
    const float* fcw = a.fcw[g];
    const float* fcb = a.fcb[g];
    const float* lw  = a.lw[g];
    const float* lb  = a.lb[g];
    __shared__ float fcs[64 * 65];
    __shared__ float fbs[64];
    for (int i = threadIdx.x; i < 64 * 65; i += 256) fcs[i] = fcw[i];
    if (threadIdx.x < 64) fbs[threadIdx.x] = fcb[threadIdx.x];
    __syncthreads();

    const int n = threadIdx.x >> 2;
    const int j0 = (threadIdx.x & 3) * 16;
    float lrow[64];
#pragma unroll
    for (int k = 0; k < 64; k++) lrow[k] = lw[n * 64 + k];

    for (int j = j0; j < j0 + 16; j++) {
        float s = 0.0f;
#pragma unroll
        for (int k = 0; k < 64; k++) s = fmaf(lrow[k], fcs[k * 65 + j + 1], s);
        Aall[(g * 64 + n) * 64 + j] = s;
    }
    if ((threadIdx.x & 3) == 0) {
        float sv = 0.0f, sc = 0.0f;
#pragma unroll
        for (int k = 0; k < 64; k++) {
            sv = fmaf(lrow[k], fcs[k * 65], sv);
            sc = fmaf(lrow[k], fbs[k], sc);
        }
        Vall[g * 64 + n] = sv;
        Call[g * 64 + n] = sc + lb[n];
    }
}

// ---------------------------------------------------------------------------
// Kernel 3: recurrence + fused classifier, SPLIT-K=2 (R9 verbatim — best
// measured: 116.8 µs; R10-R14 structural variants all regressed).
// 64 blocks x 512 threads = 8 waves = 2 waves/SIMD.
// wave = (gate g, n-half nh); lane = (n&31) | (k-half s)<<5.
// ---------------------------------------------------------------------------
__global__ __launch_bounds__(512, 1) void recur(
    const float* __restrict__ feat, const float* __restrict__ Aall,
    const float* __restrict__ Vall, const float* __restrict__ Call,
    const float* __restrict__ ew_f, const float* __restrict__ eb_f,
    const float* __restrict__ ew_i, const float* __restrict__ eb_i,
    const float* __restrict__ ew_u, const float* __restrict__ eb_u,
    const float* __restrict__ ew_o, const float* __restrict__ eb_o,
    const float* __restrict__ cls_w, const float* __restrict__ cls_b,
    float* __restrict__ out) {
    const int b = blockIdx.x;
    const int tid = threadIdx.x;
    const int wave = tid >> 6;
    const int g = wave >> 1;              // gate 0..3
    const int nh = wave & 1;              // n-half 0..1
    const int lane = tid & 63;
    const int s = lane >> 5;              // k-half 0..1
    const int n = nh * 32 + (lane & 31);  // owned output/hidden index
    const int gn = g * 64 + n;
    const float* ew  = (g == 0) ? ew_f : (g == 1) ? ew_i : (g == 2) ? ew_u : ew_o;
    const float* ebp = (g == 0) ? eb_f : (g == 1) ? eb_i : (g == 2) ? eb_u : eb_o;

    // weight slices (32 floats each) in named float4s; R4/R6 proved the
    // compiler's per-step reloads of these pipeline for free.
    const float4* ap = (const float4*)&Aall[gn * 64 + s * 32];
    const float4* ep = (const float4*)&ew[n * 64 + s * 32];
    const float4 wa0 = ap[0], wa1 = ap[1], wa2 = ap[2], wa3 = ap[3];
    const float4 wa4 = ap[4], wa5 = ap[5], wa6 = ap[6], wa7 = ap[7];
    const float4 we0 = ep[0], we1 = ep[1], we2 = ep[2], we3 = ep[3];
    const float4 we4 = ep[4], we5 = ep[5], we6 = ep[6], we7 = ep[7];
    const float vj = Vall[gn], cj = Call[gn], ebj = ebp[n];

    __shared__ __align__(16) float hx[64];
    __shared__ __align__(16) float qsh[4][64];
    __shared__ __align__(16) float acts[2][4][64];
    __shared__ __align__(16) float xts[T_];
    __shared__ float hist[T_ * 65];              // 33.3 KB
    __shared__ float cwts[NC_ * 65 + NC_];

    for (int i = tid; i < T_; i += 512) xts[i] = feat[b * T_ + i];
    for (int i = tid; i < NC_ * 64; i += 512) {
        int c = i >> 6, k = i & 63;
        cwts[c * 65 + k] = cls_w[i];
    }
    if (tid < NC_) cwts[NC_ * 65 + tid] = cls_b[tid];
    if (tid < 64) hx[tid] = 0.0f;
    float cx = 0.0f;   // cell state for unit n, replicated across waves
    __syncthreads();

    const float4* hp = (const float4*)&hx[s * 32];
    const float4* qp = (const float4*)&qsh[g][s * 32];

    for (int t = 0; t < T_; t++) {
        const float xt = xts[t];

        // ---- stage 1: q = tanh(xt*v + h @ A^T + c), split-K over s ----
        float p0 = 0, p1 = 0, p2 = 0, p3 = 0;
        {
            float4 v0 = hp[0], v1 = hp[1], v2 = hp[2], v3 = hp[3];
            float4 v4 = hp[4], v5 = hp[5], v6 = hp[6], v7 = hp[7];
            dot4(wa0, v0, p0, p1, p2, p3);
            dot4(wa1, v1, p0, p1, p2, p3);
            dot4(wa2, v2, p0, p1, p2, p3);
            dot4(wa3, v3, p0, p1, p2, p3);
            dot4(wa4, v4, p0, p1, p2, p3);
            dot4(wa5, v5, p0, p1, p2, p3);
            dot4(wa6, v6, p0, p1, p2, p3);
            dot4(wa7, v7, p0, p1, p2, p3);
        }
        float p = (p0 + p1) + (p2 + p3);
        p += __shfl_xor(p, 32, 64);                 // combine the two k-halves
        const float q = tanh_f(fmaf(xt, vj, cj) + p);
        if (s == 0) qsh[g][n] = q;
        __syncthreads();                            // barrier 1 (q exchange)

        // ---- stage 2: z = q * sigmoid(q @ ew^T + eb), split-K over s ----
        p0 = 0; p1 = 0; p2 = 0; p3 = 0;
        {
            float4 v0 = qp[0], v1 = qp[1], v2 = qp[2], v3 = qp[3];
            float4 v4 = qp[4], v5 = qp[5], v6 = qp[6], v7 = qp[7];
            dot4(we0, v0, p0, p1, p2, p3);
            dot4(we1, v1, p0, p1, p2, p3);
            dot4(we2, v2, p0, p1, p2, p3);
            dot4(we3, v3, p0, p1, p2, p3);
            dot4(we4, v4, p0, p1, p2, p3);
            dot4(we5, v5, p0, p1, p2, p3);
            dot4(we6, v6, p0, p1, p2, p3);
            dot4(we7, v7, p0, p1, p2, p3);
        }
        p = (p0 + p1) + (p2 + p3);
        p += __shfl_xor(p, 32, 64);
        const float z = q * sigmoid_f(p + ebj);
        const float act = (g == 2) ? tanh_f(z) : sigmoid_f(z);
        if (s == 0) acts[t & 1][g][n] = act;
        __syncthreads();                            // barrier 2 (acts exchange)

        // ---- cell update: every thread, own n, redundant across waves ----
        const float ff = acts[t & 1][0][n];
        const float ii = acts[t & 1][1][n];
        const float uu = acts[t & 1][2][n];
        const float oo = acts[t & 1][3][n];
        cx = fmaf(ff, cx, ii * uu);
        const float h = oo * tanh_f(cx);
        if (wave < 2 && s == 0) {                   // waves 0,1 cover n=0..63
            hx[n] = h;
            hist[t * 65 + n] = h;
        }
        __syncthreads();                            // barrier 3 (h exchange)
    }

    // fused classifier: T_*NC_ = 1280 outputs over 512 threads
#pragma unroll
    for (int j = 0; j < 3; j++) {
        const int o = j * 512 + tid;
        if (o < T_ * NC_) {
            const int r = o / 10;
            const int c = o - r * 10;
            float sacc = cwts[NC_ * 65 + c];
#pragma unroll 16
            for (int k = 0; k < 64; k++)
                sacc = fmaf(hist[r * 65 + k], cwts[c * 65 + k], sacc);
            out[((size_t)r * B_ + b) * NC_ + c] = sacc;
        }
    }
}

// ---------------------------------------------------------------------------
extern "C" void kernel_launch(void* const* d_in, const int* in_sizes, int n_in,
                              void* d_out, int out_size, void* d_ws, size_t ws_size,
                              hipStream_t stream) {
    const float* images = (const float*)d_in[0];
    const float* thr    = (const float*)d_in[1];
    const float* convw  = (const float*)d_in[2];
    const float* convb  = (const float*)d_in[3];
    const float* fcw[4]; const float* fcb[4]; const float* lw[4]; const float* lb[4];
    const float* ew[4];  const float* eb[4];
    for (int g = 0; g < 4; g++) {
        int base = 4 + g * 6;
        fcw[g] = (const float*)d_in[base + 0];
        fcb[g] = (const float*)d_in[base + 1];
        lw[g]  = (const float*)d_in[base + 2];
        lb[g]  = (const float*)d_in[base + 3];
        ew[g]  = (const float*)d_in[base + 4];
        eb[g]  = (const float*)d_in[base + 5];
    }
    const float* clsw = (const float*)d_in[28];
    const float* clsb = (const float*)d_in[29];

    float* ws   = (float*)d_ws;
    float* feat = ws;            // 8192 floats
    float* Aall = ws + 8192;     // 16384 floats
    float* Vall = ws + 24576;    // 256
    float* Call = ws + 24832;    // 256

    conv_feat<<<8192, 256, 0, stream>>>(images, convw, convb, thr, feat);

    FuseArgs fa;
    for (int g = 0; g < 4; g++) {
        fa.fcw[g] = fcw[g]; fa.fcb[g] = fcb[g];
        fa.lw[g] = lw[g];   fa.lb[g] = lb[g];
    }
    fuse_kernel<<<4, 256, 0, stream>>>(fa, Aall, Vall, Call);

    recur<<<B_, 512, 0, stream>>>(feat, Aall, Vall, Call,
                                  ew[0], eb[0], ew[1], eb[1],
                                  ew[2], eb[2], ew[3], eb[3],
                                  clsw, clsb, (float*)d_out);
}

// Round 16
// 163.280 us; speedup vs baseline: 1.5813x; 1.0483x over previous
//
#include <hip/hip_runtime.h>

// Problem constants
#define T_ 128
#define B_ 64
#define NH_ 64
#define NC_ 10

__device__ __forceinline__ float sigmoid_f(float x) {
    return 1.0f / (1.0f + __expf(-x));
}
__device__ __forceinline__ float tanh_f(float x) {
    return 1.0f - 2.0f / (1.0f + __expf(2.0f * x));
}
// 4-wide partial dot accumulate (inline fn, not macro — R8 lesson)
__device__ __forceinline__ void dot4(const float4 a, const float4 v,
                                     float& p0, float& p1, float& p2, float& p3) {
    p0 = fmaf(a.x, v.x, p0);
    p1 = fmaf(a.y, v.y, p1);
    p2 = fmaf(a.z, v.z, p2);
    p3 = fmaf(a.w, v.w, p3);
}

// ---------------------------------------------------------------------------
// Kernel 1: conv+feature, MULTI-FRAME PIPELINED. 2048 blocks x 4 frames.
// Registers prefetch frame f+1 (16 floats/thread) while frame f computes
// from the single LDS buffer (R9-proven b128 layout, IMP=68 anti-conflict
// pitch). HBM latency hides under the ~900-cyc compute. R15's direct-global
// variant regressed (L1 thrash at 8 blocks/CU x 16KB); LDS staging reads
// each global byte exactly once.
// ---------------------------------------------------------------------------
#define IMP 68
#define FPB 4
__global__ __launch_bounds__(256) void conv_feat(const float* __restrict__ img,
                                                 const float* __restrict__ cw,
                                                 const float* __restrict__ cb,
                                                 const float* __restrict__ thr,
                                                 float* __restrict__ feat) {
    __shared__ __align__(16) float im[64 * IMP];
    __shared__ float wsum[4];
    const int tid = threadIdx.x;
    const float* base = img + (size_t)blockIdx.x * FPB * 4096;
    const float w0 = cw[0], w1 = cw[1], w2 = cw[2], w3 = cw[3], w4 = cw[4],
                w5 = cw[5], w6 = cw[6], w7 = cw[7], w8 = cw[8];
    const float bias = cb[0] - thr[0];

    const int rr = tid >> 4;          // staging row within each 16-row group
    const int cc = (tid & 15) * 4;    // staging col
    const int r  = tid >> 2;          // compute: output row 0..63 (62,63 idle)
    const int c0 = (tid & 3) * 16;    // compute: output col base
    const int wv = tid >> 6, ln = tid & 63;

    float4 pf0 = *(const float4*)&base[(0 * 256 + tid) * 4];
    float4 pf1 = *(const float4*)&base[(1 * 256 + tid) * 4];
    float4 pf2 = *(const float4*)&base[(2 * 256 + tid) * 4];
    float4 pf3 = *(const float4*)&base[(3 * 256 + tid) * 4];

    for (int f = 0; f < FPB; f++) {
        // stage current frame from regs (waits only on its own loads)
        *(float4*)&im[(0 * 16 + rr) * IMP + cc] = pf0;
        *(float4*)&im[(1 * 16 + rr) * IMP + cc] = pf1;
        *(float4*)&im[(2 * 16 + rr) * IMP + cc] = pf2;
        *(float4*)&im[(3 * 16 + rr) * IMP + cc] = pf3;
        // issue next frame's loads — they complete during this frame's compute
        if (f + 1 < FPB) {
            const float* s = base + (size_t)(f + 1) * 4096;
            pf0 = *(const float4*)&s[(0 * 256 + tid) * 4];
            pf1 = *(const float4*)&s[(1 * 256 + tid) * 4];
            pf2 = *(const float4*)&s[(2 * 256 + tid) * 4];
            pf3 = *(const float4*)&s[(3 * 256 + tid) * 4];
        }
        __syncthreads();  // B1: staging visible

        float sum = 0.0f;
        if (r < 62) {
            const int ncols = (c0 == 48) ? 14 : 16;
            float acc[16];
#pragma unroll
            for (int x = 0; x < 16; x++) acc[x] = bias;
#pragma unroll
            for (int dr = 0; dr < 3; dr++) {
                float rb[20];
#pragma unroll
                for (int j = 0; j < 5; j++) {
                    float4 v = *(const float4*)&im[(r + dr) * IMP + c0 + j * 4];
                    rb[j * 4 + 0] = v.x; rb[j * 4 + 1] = v.y;
                    rb[j * 4 + 2] = v.z; rb[j * 4 + 3] = v.w;
                }
                const float k0 = (dr == 0) ? w0 : (dr == 1) ? w3 : w6;
                const float k1 = (dr == 0) ? w1 : (dr == 1) ? w4 : w7;
                const float k2 = (dr == 0) ? w2 : (dr == 1) ? w5 : w8;
#pragma unroll
                for (int x = 0; x < 16; x++) {
                    acc[x] = fmaf(rb[x], k0, acc[x]);
                    acc[x] = fmaf(rb[x + 1], k1, acc[x]);
                    acc[x] = fmaf(rb[x + 2], k2, acc[x]);
                }
            }
#pragma unroll
            for (int x = 0; x < 16; x++)
                if (x < ncols) sum += sigmoid_f(acc[x]);
        }
#pragma unroll
        for (int off = 32; off >= 1; off >>= 1) sum += __shfl_down(sum, off, 64);
        if (ln == 0) wsum[wv] = sum;
        __syncthreads();  // B2: wsum visible; all im reads done (WAR for next stage)
        if (tid == 0)
            feat[blockIdx.x * FPB + f] =
                (wsum[0] + wsum[1] + wsum[2] + wsum[3]) * (1.0f / 3844.0f);
    }
}

// ---------------------------------------------------------------------------
// Kernel 2: fold fc+lw per gate (unchanged). grid = 4, 256 threads.
// ---------------------------------------------------------------------------
struct FuseArgs {
    const float* fcw[4];
    const float* fcb[4];
    const float* lw[4];
    const float* lb[4];
};

__global__ __launch_bounds__(256) void fuse_kernel(FuseArgs a, float* __restrict__ Aall,
                                                   float* __restrict__ Vall,
                                                   float* __restrict__ Call) {
    const int g = blockIdx.x;
    const float* fcw = a.fcw[g];
    const float* fcb = a.fcb[g];
    const float* lw  = a.lw[g];
    const float* lb  = a.lb[g];
    __shared__ float fcs[64 * 65];
    __shared__ float fbs[64];
    for (int i = threadIdx.x; i < 64 * 65; i += 256) fcs[i] = fcw[i];
    if (threadIdx.x < 64) fbs[threadIdx.x] = fcb[threadIdx.x];
    __syncthreads();

    const int n = threadIdx.x >> 2;
    const int j0 = (threadIdx.x & 3) * 16;
    float lrow[64];
#pragma unroll
    for (int k = 0; k < 64; k++) lrow[k] = lw[n * 64 + k];

    for (int j = j0; j < j0 + 16; j++) {
        float s = 0.0f;
#pragma unroll
        for (int k = 0; k < 64; k++) s = fmaf(lrow[k], fcs[k * 65 + j + 1], s);
        Aall[(g * 64 + n) * 64 + j] = s;
    }
    if ((threadIdx.x & 3) == 0) {
        float sv = 0.0f, sc = 0.0f;
#pragma unroll
        for (int k = 0; k < 64; k++) {
            sv = fmaf(lrow[k], fcs[k * 65], sv);
            sc = fmaf(lrow[k], fbs[k], sc);
        }
        Vall[g * 64 + n] = sv;
        Call[g * 64 + n] = sc + lb[n];
    }
}

// ---------------------------------------------------------------------------
// Kernel 3: recurrence + fused classifier, SPLIT-K=2, TWO barriers/step.
// R9 structure (best measured) with barrier 3 removed: every thread already
// computes the cell update redundantly; now each wave writes its OWN hx copy
// (hx8[wave][np], np = s*32+(lane&31) covers 0..63 per wave) and stage 1
// reads its own wave's copy — own-wave DS ordering, no barrier needed.
// qsh/acts WAR hazards remain fenced by barrier 2 (reads pre-B2, conflicting
// writes post-B2 of the same step).
// ---------------------------------------------------------------------------
__global__ __launch_bounds__(512, 1) void recur(
    const float* __restrict__ feat, const float* __restrict__ Aall,
    const float* __restrict__ Vall, const float* __restrict__ Call,
    const float* __restrict__ ew_f, const float* __restrict__ eb_f,
    const float* __restrict__ ew_i, const float* __restrict__ eb_i,
    const float* __restrict__ ew_u, const float* __restrict__ eb_u,
    const float* __restrict__ ew_o, const float* __restrict__ eb_o,
    const float* __restrict__ cls_w, const float* __restrict__ cls_b,
    float* __restrict__ out) {
    const int b = blockIdx.x;
    const int tid = threadIdx.x;
    const int wave = tid >> 6;
    const int g = wave >> 1;              // gate 0..3
    const int nh = wave & 1;              // n-half 0..1
    const int lane = tid & 63;
    const int s = lane >> 5;              // k-half 0..1
    const int n = nh * 32 + (lane & 31);  // owned output index (q, acts)
    const int np = s * 32 + (lane & 31);  // owned cell index (cx, h)
    const int gn = g * 64 + n;
    const float* ew  = (g == 0) ? ew_f : (g == 1) ? ew_i : (g == 2) ? ew_u : ew_o;
    const float* ebp = (g == 0) ? eb_f : (g == 1) ? eb_i : (g == 2) ? eb_u : eb_o;

    // weight slices (32 floats each) in named float4s; R4/R6 proved the
    // compiler's per-step reloads of these pipeline for free.
    const float4* ap = (const float4*)&Aall[gn * 64 + s * 32];
    const float4* ep = (const float4*)&ew[n * 64 + s * 32];
    const float4 wa0 = ap[0], wa1 = ap[1], wa2 = ap[2], wa3 = ap[3];
    const float4 wa4 = ap[4], wa5 = ap[5], wa6 = ap[6], wa7 = ap[7];
    const float4 we0 = ep[0], we1 = ep[1], we2 = ep[2], we3 = ep[3];
    const float4 we4 = ep[4], we5 = ep[5], we6 = ep[6], we7 = ep[7];
    const float vj = Vall[gn], cj = Call[gn], ebj = ebp[n];

    __shared__ __align__(16) float hx8[8][64];   // per-wave private h copies
    __shared__ __align__(16) float qsh[4][64];
    __shared__ __align__(16) float acts[2][4][64];
    __shared__ __align__(16) float xts[T_];
    __shared__ float hist[T_ * 65];              // 33.3 KB
    __shared__ float cwts[NC_ * 65 + NC_];

    for (int i = tid; i < T_; i += 512) xts[i] = feat[b * T_ + i];
    for (int i = tid; i < NC_ * 64; i += 512) {
        int c = i >> 6, k = i & 63;
        cwts[c * 65 + k] = cls_w[i];
    }
    if (tid < NC_) cwts[NC_ * 65 + tid] = cls_b[tid];
    hx8[wave][lane] = 0.0f;            // each wave zeroes its own copy
    float cx = 0.0f;                   // cell state for unit np
    __syncthreads();

    const float4* hp = (const float4*)&hx8[wave][s * 32];
    const float4* qp = (const float4*)&qsh[g][s * 32];

    for (int t = 0; t < T_; t++) {
        const float xt = xts[t];

        // ---- stage 1: q = tanh(xt*v + h @ A^T + c), own-wave h copy ----
        float p0 = 0, p1 = 0, p2 = 0, p3 = 0;
        {
            float4 v0 = hp[0], v1 = hp[1], v2 = hp[2], v3 = hp[3];
            float4 v4 = hp[4], v5 = hp[5], v6 = hp[6], v7 = hp[7];
            dot4(wa0, v0, p0, p1, p2, p3);
            dot4(wa1, v1, p0, p1, p2, p3);
            dot4(wa2, v2, p0, p1, p2, p3);
            dot4(wa3, v3, p0, p1, p2, p3);
            dot4(wa4, v4, p0, p1, p2, p3);
            dot4(wa5, v5, p0, p1, p2, p3);
            dot4(wa6, v6, p0, p1, p2, p3);
            dot4(wa7, v7, p0, p1, p2, p3);
        }
        float p = (p0 + p1) + (p2 + p3);
        p += __shfl_xor(p, 32, 64);                 // combine the two k-halves
        const float q = tanh_f(fmaf(xt, vj, cj) + p);
        if (s == 0) qsh[g][n] = q;
        __syncthreads();                            // barrier 1 (q exchange)

        // ---- stage 2: z = q * sigmoid(q @ ew^T + eb), split-K over s ----
        p0 = 0; p1 = 0; p2 = 0; p3 = 0;
        {
            float4 v0 = qp[0], v1 = qp[1], v2 = qp[2], v3 = qp[3];
            float4 v4 = qp[4], v5 = qp[5], v6 = qp[6], v7 = qp[7];
            dot4(we0, v0, p0, p1, p2, p3);
            dot4(we1, v1, p0, p1, p2, p3);
            dot4(we2, v2, p0, p1, p2, p3);
            dot4(we3, v3, p0, p1, p2, p3);
            dot4(we4, v4, p0, p1, p2, p3);
            dot4(we5, v5, p0, p1, p2, p3);
            dot4(we6, v6, p0, p1, p2, p3);
            dot4(we7, v7, p0, p1, p2, p3);
        }
        p = (p0 + p1) + (p2 + p3);
        p += __shfl_xor(p, 32, 64);
        const float z = q * sigmoid_f(p + ebj);
        const float act = (g == 2) ? tanh_f(z) : sigmoid_f(z);
        if (s == 0) acts[t & 1][g][n] = act;
        __syncthreads();                            // barrier 2 (acts exchange)

        // ---- cell update for np: ALL waves, bitwise-identical results ----
        const float ff = acts[t & 1][0][np];
        const float ii = acts[t & 1][1][np];
        const float uu = acts[t & 1][2][np];
        const float oo = acts[t & 1][3][np];
        cx = fmaf(ff, cx, ii * uu);
        const float h = oo * tanh_f(cx);
        hx8[wave][np] = h;                 // own-wave copy; no barrier needed
        if (wave == 0) hist[t * 65 + np] = h;
    }
    __syncthreads();  // hist complete

    // fused classifier: T_*NC_ = 1280 outputs over 512 threads
#pragma unroll
    for (int j = 0; j < 3; j++) {
        const int o = j * 512 + tid;
        if (o < T_ * NC_) {
            const int r = o / 10;
            const int c = o - r * 10;
            float sacc = cwts[NC_ * 65 + c];
#pragma unroll 16
            for (int k = 0; k < 64; k++)
                sacc = fmaf(hist[r * 65 + k], cwts[c * 65 + k], sacc);
            out[((size_t)r * B_ + b) * NC_ + c] = sacc;
        }
    }
}

// ---------------------------------------------------------------------------
extern "C" void kernel_launch(void* const* d_in, const int* in_sizes, int n_in,
                              void* d_out, int out_size, void* d_ws, size_t ws_size,
                              hipStream_t stream) {
    const float* images = (const float*)d_in[0];
    const float* thr    = (const float*)d_in[1];
    const float* convw  = (const float*)d_in[2];
    const float* convb  = (const float*)d_in[3];
    const float* fcw[4]; const float* fcb[4]; const float* lw[4]; const float* lb[4];
    const float* ew[4];  const float* eb[4];
    for (int g = 0; g < 4; g++) {
        int base = 4 + g * 6;
        fcw[g] = (const float*)d_in[base + 0];
        fcb[g] = (const float*)d_in[base + 1];
        lw[g]  = (const float*)d_in[base + 2];
        lb[g]  = (const float*)d_in[base + 3];
        ew[g]  = (const float*)d_in[base + 4];
        eb[g]  = (const float*)d_in[base + 5];
    }
    const float* clsw = (const float*)d_in[28];
    const float* clsb = (const float*)d_in[29];

    float* ws   = (float*)d_ws;
    float* feat = ws;            // 8192 floats
    float* Aall = ws + 8192;     // 16384 floats
    float* Vall = ws + 24576;    // 256
    float* Call = ws + 24832;    // 256

    conv_feat<<<8192 / FPB, 256, 0, stream>>>(images, convw, convb, thr, feat);

    FuseArgs fa;
    for (int g = 0; g < 4; g++) {
        fa.fcw[g] = fcw[g]; fa.fcb[g] = fcb[g];
        fa.lw[g] = lw[g];   fa.lb[g] = lb[g];
    }
    fuse_kernel<<<4, 256, 0, stream>>>(fa, Aall, Vall, Call);

    recur<<<B_, 512, 0, stream>>>(feat, Aall, Vall, Call,
                                  ew[0], eb[0], ew[1], eb[1],
                                  ew[2], eb[2], ew[3], eb[3],
                                  clsw, clsb, (float*)d_out);
}

// Round 17
// 158.490 us; speedup vs baseline: 1.6290x; 1.0302x over previous
//
#include <hip/hip_runtime.h>

// Problem constants
#define T_ 128
#define B_ 64
#define NH_ 64
#define NC_ 10

__device__ __forceinline__ float sigmoid_f(float x) {
    return 1.0f / (1.0f + __expf(-x));
}
__device__ __forceinline__ float tanh_f(float x) {
    return 1.0f - 2.0f / (1.0f + __expf(2.0f * x));
}
// 4-wide partial dot accumulate (inline fn, not macro — R8 lesson)
__device__ __forceinline__ void dot4(const float4 a, const float4 v,
                                     float& p0, float& p1, float& p2, float& p3) {
    p0 = fmaf(a.x, v.x, p0);
    p1 = fmaf(a.y, v.y, p1);
    p2 = fmaf(a.z, v.z, p2);
    p3 = fmaf(a.w, v.w, p3);
}

// ---------------------------------------------------------------------------
// Kernel 1: per-frame 3x3 VALID conv -> sigmoid(logit-thr) -> spatial mean.
// grid = 8192 x 256 — R9's exact version (best measured conv: ~46.7 µs
// section). R15 direct-global (L1 thrash) and R16 multi-frame prefetch
// (barrier vmcnt drain defeats pipelining; fewer blocks removed the
// block-turnover stagger) both regressed.
// ---------------------------------------------------------------------------
#define IMP 68
__global__ __launch_bounds__(256) void conv_feat(const float* __restrict__ img,
                                                 const float* __restrict__ cw,
                                                 const float* __restrict__ cb,
                                                 const float* __restrict__ thr,
                                                 float* __restrict__ feat) {
    __shared__ __align__(16) float im[64 * IMP];
    __shared__ float wsum[4];
    const int tid = threadIdx.x;
    const float* src = img + (size_t)blockIdx.x * 4096;
#pragma unroll
    for (int i = 0; i < 4; i++) {
        const int idx = i * 256 + tid;
        const int row = idx >> 4, c4 = idx & 15;
        *(float4*)&im[row * IMP + c4 * 4] = *(const float4*)&src[idx * 4];
    }
    const float w0 = cw[0], w1 = cw[1], w2 = cw[2], w3 = cw[3], w4 = cw[4],
                w5 = cw[5], w6 = cw[6], w7 = cw[7], w8 = cw[8];
    const float bias = cb[0] - thr[0];
    __syncthreads();

    const int r  = tid >> 2;
    const int c0 = (tid & 3) * 16;
    float sum = 0.0f;
    if (r < 62) {
        const int ncols = (c0 == 48) ? 14 : 16;
        float acc[16];
#pragma unroll
        for (int x = 0; x < 16; x++) acc[x] = bias;
#pragma unroll
        for (int dr = 0; dr < 3; dr++) {
            float rb[20];
#pragma unroll
            for (int j = 0; j < 5; j++) {
                float4 v = *(const float4*)&im[(r + dr) * IMP + c0 + j * 4];
                rb[j * 4 + 0] = v.x; rb[j * 4 + 1] = v.y;
                rb[j * 4 + 2] = v.z; rb[j * 4 + 3] = v.w;
            }
            const float k0 = (dr == 0) ? w0 : (dr == 1) ? w3 : w6;
            const float k1 = (dr == 0) ? w1 : (dr == 1) ? w4 : w7;
            const float k2 = (dr == 0) ? w2 : (dr == 1) ? w5 : w8;
#pragma unroll
            for (int x = 0; x < 16; x++) {
                acc[x] = fmaf(rb[x], k0, acc[x]);
                acc[x] = fmaf(rb[x + 1], k1, acc[x]);
                acc[x] = fmaf(rb[x + 2], k2, acc[x]);
            }
        }
#pragma unroll
        for (int x = 0; x < 16; x++)
            if (x < ncols) sum += sigmoid_f(acc[x]);
    }
#pragma unroll
    for (int off = 32; off >= 1; off >>= 1) sum += __shfl_down(sum, off, 64);
    const int wv = tid >> 6, ln = tid & 63;
    if (ln == 0) wsum[wv] = sum;
    __syncthreads();
    if (tid == 0)
        feat[blockIdx.x] = (wsum[0] + wsum[1] + wsum[2] + wsum[3]) * (1.0f / 3844.0f);
}

// ---------------------------------------------------------------------------
// Kernel 2: fold fc+lw per gate (unchanged). grid = 4, 256 threads.
// ---------------------------------------------------------------------------
struct FuseArgs {
    const float* fcw[4];
    const float* fcb[4];
    const float* lw[4];
    const float* lb[4];
};

__global__ __launch_bounds__(256) void fuse_kernel(FuseArgs a, float* __restrict__ Aall,
                                                   float* __restrict__ Vall,
                                                   float* __restrict__ Call) {
    const int g = blockIdx.x;
    const float* fcw = a.fcw[g];
    const float* fcb = a.fcb[g];
    const float* lw  = a.lw[g];
    const float* lb  = a.lb[g];
    __shared__ float fcs[64 * 65];
    __shared__ float fbs[64];
    for (int i = threadIdx.x; i < 64 * 65; i += 256) fcs[i] = fcw[i];
    if (threadIdx.x < 64) fbs[threadIdx.x] = fcb[threadIdx.x];
    __syncthreads();

    const int n = threadIdx.x >> 2;
    const int j0 = (threadIdx.x & 3) * 16;
    float lrow[64];
#pragma unroll
    for (int k = 0; k < 64; k++) lrow[k] = lw[n * 64 + k];

    for (int j = j0; j < j0 + 16; j++) {
        float s = 0.0f;
#pragma unroll
        for (int k = 0; k < 64; k++) s = fmaf(lrow[k], fcs[k * 65 + j + 1], s);
        Aall[(g * 64 + n) * 64 + j] = s;
    }
    if ((threadIdx.x & 3) == 0) {
        float sv = 0.0f, sc = 0.0f;
#pragma unroll
        for (int k = 0; k < 64; k++) {
            sv = fmaf(lrow[k], fcs[k * 65], sv);
            sc = fmaf(lrow[k], fbs[k], sc);
        }
        Vall[g * 64 + n] = sv;
        Call[g * 64 + n] = sc + lb[n];
    }
}

// ---------------------------------------------------------------------------
// Kernel 3: recurrence + fused classifier, SPLIT-K=2, TWO barriers/step
// (R16 verbatim — best measured: 112.5 µs). 64 blocks x 512 threads.
// wave = (gate g, n-half nh); lane = (n&31) | (k-half s)<<5.
// Cell update redundant on all waves; per-wave private hx copies remove
// barrier 3 (own-wave DS ordering).
// ---------------------------------------------------------------------------
__global__ __launch_bounds__(512, 1) void recur(
    const float* __restrict__ feat, const float* __restrict__ Aall,
    const float* __restrict__ Vall, const float* __restrict__ Call,
    const float* __restrict__ ew_f, const float* __restrict__ eb_f,
    const float* __restrict__ ew_i, const float* __restrict__ eb_i,
    const float* __restrict__ ew_u, const float* __restrict__ eb_u,
    const float* __restrict__ ew_o, const float* __restrict__ eb_o,
    const float* __restrict__ cls_w, const float* __restrict__ cls_b,
    float* __restrict__ out) {
    const int b = blockIdx.x;
    const int tid = threadIdx.x;
    const int wave = tid >> 6;
    const int g = wave >> 1;              // gate 0..3
    const int nh = wave & 1;              // n-half 0..1
    const int lane = tid & 63;
    const int s = lane >> 5;              // k-half 0..1
    const int n = nh * 32 + (lane & 31);  // owned output index (q, acts)
    const int np = s * 32 + (lane & 31);  // owned cell index (cx, h)
    const int gn = g * 64 + n;
    const float* ew  = (g == 0) ? ew_f : (g == 1) ? ew_i : (g == 2) ? ew_u : ew_o;
    const float* ebp = (g == 0) ? eb_f : (g == 1) ? eb_i : (g == 2) ? eb_u : eb_o;

    // weight slices (32 floats each) in named float4s; R4/R6 proved the
    // compiler's per-step reloads of these pipeline for free.
    const float4* ap = (const float4*)&Aall[gn * 64 + s * 32];
    const float4* ep = (const float4*)&ew[n * 64 + s * 32];
    const float4 wa0 = ap[0], wa1 = ap[1], wa2 = ap[2], wa3 = ap[3];
    const float4 wa4 = ap[4], wa5 = ap[5], wa6 = ap[6], wa7 = ap[7];
    const float4 we0 = ep[0], we1 = ep[1], we2 = ep[2], we3 = ep[3];
    const float4 we4 = ep[4], we5 = ep[5], we6 = ep[6], we7 = ep[7];
    const float vj = Vall[gn], cj = Call[gn], ebj = ebp[n];

    __shared__ __align__(16) float hx8[8][64];   // per-wave private h copies
    __shared__ __align__(16) float qsh[4][64];
    __shared__ __align__(16) float acts[2][4][64];
    __shared__ __align__(16) float xts[T_];
    __shared__ float hist[T_ * 65];              // 33.3 KB
    __shared__ float cwts[NC_ * 65 + NC_];

    for (int i = tid; i < T_; i += 512) xts[i] = feat[b * T_ + i];
    for (int i = tid; i < NC_ * 64; i += 512) {
        int c = i >> 6, k = i & 63;
        cwts[c * 65 + k] = cls_w[i];
    }
    if (tid < NC_) cwts[NC_ * 65 + tid] = cls_b[tid];
    hx8[wave][lane] = 0.0f;            // each wave zeroes its own copy
    float cx = 0.0f;                   // cell state for unit np
    __syncthreads();

    const float4* hp = (const float4*)&hx8[wave][s * 32];
    const float4* qp = (const float4*)&qsh[g][s * 32];

    for (int t = 0; t < T_; t++) {
        const float xt = xts[t];

        // ---- stage 1: q = tanh(xt*v + h @ A^T + c), own-wave h copy ----
        float p0 = 0, p1 = 0, p2 = 0, p3 = 0;
        {
            float4 v0 = hp[0], v1 = hp[1], v2 = hp[2], v3 = hp[3];
            float4 v4 = hp[4], v5 = hp[5], v6 = hp[6], v7 = hp[7];
            dot4(wa0, v0, p0, p1, p2, p3);
            dot4(wa1, v1, p0, p1, p2, p3);
            dot4(wa2, v2, p0, p1, p2, p3);
            dot4(wa3, v3, p0, p1, p2, p3);
            dot4(wa4, v4, p0, p1, p2, p3);
            dot4(wa5, v5, p0, p1, p2, p3);
            dot4(wa6, v6, p0, p1, p2, p3);
            dot4(wa7, v7, p0, p1, p2, p3);
        }
        float p = (p0 + p1) + (p2 + p3);
        p += __shfl_xor(p, 32, 64);                 // combine the two k-halves
        const float q = tanh_f(fmaf(xt, vj, cj) + p);
        if (s == 0) qsh[g][n] = q;
        __syncthreads();                            // barrier 1 (q exchange)

        // ---- stage 2: z = q * sigmoid(q @ ew^T + eb), split-K over s ----
        p0 = 0; p1 = 0; p2 = 0; p3 = 0;
        {
            float4 v0 = qp[0], v1 = qp[1], v2 = qp[2], v3 = qp[3];
            float4 v4 = qp[4], v5 = qp[5], v6 = qp[6], v7 = qp[7];
            dot4(we0, v0, p0, p1, p2, p3);
            dot4(we1, v1, p0, p1, p2, p3);
            dot4(we2, v2, p0, p1, p2, p3);
            dot4(we3, v3, p0, p1, p2, p3);
            dot4(we4, v4, p0, p1, p2, p3);
            dot4(we5, v5, p0, p1, p2, p3);
            dot4(we6, v6, p0, p1, p2, p3);
            dot4(we7, v7, p0, p1, p2, p3);
        }
        p = (p0 + p1) + (p2 + p3);
        p += __shfl_xor(p, 32, 64);
        const float z = q * sigmoid_f(p + ebj);
        const float act = (g == 2) ? tanh_f(z) : sigmoid_f(z);
        if (s == 0) acts[t & 1][g][n] = act;
        __syncthreads();                            // barrier 2 (acts exchange)

        // ---- cell update for np: ALL waves, bitwise-identical results ----
        const float ff = acts[t & 1][0][np];
        const float ii = acts[t & 1][1][np];
        const float uu = acts[t & 1][2][np];
        const float oo = acts[t & 1][3][np];
        cx = fmaf(ff, cx, ii * uu);
        const float h = oo * tanh_f(cx);
        hx8[wave][np] = h;                 // own-wave copy; no barrier needed
        if (wave == 0) hist[t * 65 + np] = h;
    }
    __syncthreads();  // hist complete

    // fused classifier: T_*NC_ = 1280 outputs over 512 threads
#pragma unroll
    for (int j = 0; j < 3; j++) {
        const int o = j * 512 + tid;
        if (o < T_ * NC_) {
            const int r = o / 10;
            const int c = o - r * 10;
            float sacc = cwts[NC_ * 65 + c];
#pragma unroll 16
            for (int k = 0; k < 64; k++)
                sacc = fmaf(hist[r * 65 + k], cwts[c * 65 + k], sacc);
            out[((size_t)r * B_ + b) * NC_ + c] = sacc;
        }
    }
}

// ---------------------------------------------------------------------------
extern "C" void kernel_launch(void* const* d_in, const int* in_sizes, int n_in,
                              void* d_out, int out_size, void* d_ws, size_t ws_size,
                              hipStream_t stream) {
    const float* images = (const float*)d_in[0];
    const float* thr    = (const float*)d_in[1];
    const float* convw  = (const float*)d_in[2];
    const float* convb  = (const float*)d_in[3];
    const float* fcw[4]; const float* fcb[4]; const float* lw[4]; const float* lb[4];
    const float* ew[4];  const float* eb[4];
    for (int g = 0; g < 4; g++) {
        int base = 4 + g * 6;
        fcw[g] = (const float*)d_in[base + 0];
        fcb[g] = (const float*)d_in[base + 1];
        lw[g]  = (const float*)d_in[base + 2];
        lb[g]  = (const float*)d_in[base + 3];
        ew[g]  = (const float*)d_in[base + 4];
        eb[g]  = (const float*)d_in[base + 5];
    }
    const float* clsw = (const float*)d_in[28];
    const float* clsb = (const float*)d_in[29];

    float* ws   = (float*)d_ws;
    float* feat = ws;            // 8192 floats
    float* Aall = ws + 8192;     // 16384 floats
    float* Vall = ws + 24576;    // 256
    float* Call = ws + 24832;    // 256

    conv_feat<<<8192, 256, 0, stream>>>(images, convw, convb, thr, feat);

    FuseArgs fa;
    for (int g = 0; g < 4; g++) {
        fa.fcw[g] = fcw[g]; fa.fcb[g] = fcb[g];
        fa.lw[g] = lw[g];   fa.lb[g] = lb[g];
    }
    fuse_kernel<<<4, 256, 0, stream>>>(fa, Aall, Vall, Call);

    recur<<<B_, 512, 0, stream>>>(feat, Aall, Vall, Call,
                                  ew[0], eb[0], ew[1], eb[1],
                                  ew[2], eb[2], ew[3], eb[3],
                                  clsw, clsb, (float*)d_out);
}